// Round 8
// baseline (16853.499 us; speedup 1.0000x reference)
//
#include <hip/hip_runtime.h>

#define HID 64
#define NF 8

typedef float f2 __attribute__((ext_vector_type(2)));
typedef float f4 __attribute__((ext_vector_type(4)));

template <int CTRL>
__device__ __forceinline__ float qp(float x) {
  return __int_as_float(
      __builtin_amdgcn_update_dpp(0, __float_as_int(x), CTRL, 0xF, 0xF, true));
}
__device__ __forceinline__ float sigm(float x) {
  float e = __expf(-x);
  return __fdividef(1.0f, 1.0f + e);
}
__device__ __forceinline__ float tanhe(float x) {
  float e = __expf(-2.0f * x);
  return __fdividef(2.0f, 1.0f + e) - 1.0f;
}
__device__ __forceinline__ int ldc(int* p) {
  return __hip_atomic_load(p, __ATOMIC_ACQUIRE, __HIP_MEMORY_SCOPE_WORKGROUP);
}
__device__ __forceinline__ void stc(int* p, int v) {
  __hip_atomic_store(p, v, __ATOMIC_RELEASE, __HIP_MEMORY_SCOPE_WORKGROUP);
}

// 256 threads = 4 waves, 1/SIMD, each wave a private pipeline stage:
//  wave0: layer-0 LSTM (64 units, lane=unit). quad-K-split dot (4 b128/wave),
//         rotated-slot DPP transpose-reduce (lane k slot [i][j] = unit
//         (k+i)&3, gate j), act fully in-lane, c/h in registers.
//  wave1: P[s] = Wih1 @ h0[s]          (same dot scheme, no act)
//  wave2: h1[s] = act(P[s] + Whh1 @ h1[s-1])   (lane=unit, act in-lane)
//  wave3: x-proj (xprj[t+2]), hiddenfc+outputfc (step t-4), obuf/tbuf IO.
// Sync: 4 single-writer LDS phase counters; each wave polls exactly ONE
// upstream counter per phase + releases its own. Chain L0->L1a->L1b->head->L0
// has >=1 phase lag per edge -> rate = max(stage). Spread<=2; depth-8 rings.
__global__ __launch_bounds__(256, 1) void decoder_p8(
    const float* __restrict__ h0in, const float* __restrict__ c0in,
    const float* __restrict__ diffp, const float* __restrict__ target,
    const float* __restrict__ Wih0, const float* __restrict__ Whh0,
    const float* __restrict__ bih0, const float* __restrict__ bhh0,
    const float* __restrict__ Wih1, const float* __restrict__ Whh1,
    const float* __restrict__ bih1, const float* __restrict__ bhh1,
    const float* __restrict__ Whid, const float* __restrict__ bhidp,
    const float* __restrict__ Woutp, const float* __restrict__ boutp,
    float* __restrict__ outp, const int T)
{
  const int tid = threadIdx.x;
  const int wv  = tid >> 6;
  const int l   = tid & 63;
  const int q   = l >> 2;
  const int k   = l & 3;

  __shared__ alignas(256) float h0L[8][64];
  __shared__ alignas(256) float h1L[8][64];
  __shared__ alignas(256) float Pld[4][8][64];   // [gate][slot][unit]
  __shared__ alignas(256) float xS[4][8][64];    // [gate][slot][unit]
  __shared__ alignas(256) float hidb[32];
  __shared__ alignas(256) float obuf[64 * NF];
  __shared__ alignas(256) float tbuf[2][32 * NF];
  __shared__ int cnt[4];   // 0=L0, 1=L1a, 2=L1b, 3=head

  f2 wq[128];              // per-wave weights (overlaid roles)
  float bg[4] = {0, 0, 0, 0};
  float xd4[4] = {0, 0, 0, 0};
  float bh_r = 0.f, bo_r = 0.f;
  float cS = 0.f, hS = 0.f;

  // ================= INIT =================
  if (wv <= 2) {
    const float* W = (wv == 0) ? Whh0 : (wv == 1) ? Wih1 : Whh1;
    #pragma unroll
    for (int i = 0; i < 4; ++i)
      #pragma unroll
      for (int j = 0; j < 4; ++j) {
        const int row = 64 * j + 4 * q + ((k + i) & 3);
        const float* rp = W + row * HID + 16 * k;
        #pragma unroll
        for (int c = 0; c < 4; ++c) {
          f4 v = *(const f4*)(rp + 4 * c);
          wq[(i * 4 + j) * 8 + 2 * c]     = v.lo;
          wq[(i * 4 + j) * 8 + 2 * c + 1] = v.hi;
        }
      }
    if (wv == 0) {
      #pragma unroll
      for (int j = 0; j < 4; ++j) bg[j] = bih0[64 * j + l] + bhh0[64 * j + l];
      cS = c0in[l];
      h0L[7][l] = h0in[l];
    } else if (wv == 2) {
      #pragma unroll
      for (int j = 0; j < 4; ++j) bg[j] = bih1[64 * j + l] + bhh1[64 * j + l];
      cS = c0in[64 + l];
      h1L[7][l] = h0in[64 + l];
    }
  } else {
    // head: wx rows 64j+l -> wq[0..15]; whid -> wq[16..31]; wout -> wq[32..35]
    #pragma unroll
    for (int j = 0; j < 4; ++j) {
      const float* ra = Wih0 + (64 * j + l) * 14;
      #pragma unroll
      for (int c = 0; c < 4; ++c) wq[j * 4 + c] = (f2){ra[2 * c], ra[2 * c + 1]};
      float s = 0.f;
      #pragma unroll
      for (int m = 0; m < 6; ++m) s += ra[8 + m] * diffp[m];
      xd4[j] = s;
    }
    #pragma unroll
    for (int i = 0; i < 2; ++i) {
      const int row = 2 * q + ((k + i) & 1);
      const float* rp = Whid + row * HID + 16 * k;
      #pragma unroll
      for (int c = 0; c < 4; ++c) {
        f4 v = *(const f4*)(rp + 4 * c);
        wq[16 + i * 8 + 2 * c]     = v.lo;
        wq[16 + i * 8 + 2 * c + 1] = v.hi;
      }
    }
    if (k < 2) bh_r = bhidp[2 * q + k];
    if (q < 8) {
      const float* rp = Woutp + q * 32 + 8 * k;
      f4 a = *(const f4*)rp, b = *(const f4*)(rp + 4);
      wq[32] = a.lo; wq[33] = a.hi; wq[34] = b.lo; wq[35] = b.hi;
      bo_r = boutp[q];
    }
    // tbuf chunks 0,1
    *(f4*)&((float*)tbuf)[l * 8]     = *(const f4*)&target[l * 8];
    *(f4*)&((float*)tbuf)[l * 8 + 4] = *(const f4*)&target[l * 8 + 4];
    // xprj[1] from target[0] (pre-loop, slot 1)
    {
      f4 t0 = *(const f4*)&target[0];
      f4 t1 = *(const f4*)&target[4];
      #pragma unroll
      for (int j = 0; j < 4; ++j) {
        f2 s = wq[j * 4 + 0] * t0.lo;
        s += wq[j * 4 + 1] * t0.hi;
        s += wq[j * 4 + 2] * t1.lo;
        s += wq[j * 4 + 3] * t1.hi;
        xS[j][1][l] = xd4[j] + s.x + s.y;
      }
    }
  }
  if (tid < 4) cnt[tid] = 0;
  __syncthreads();

  const int tend = T + 3;

  // ================= MAIN: divergent per-wave loops =================
  if (wv == 0) {
    // ---------------- layer 0 ----------------
    for (int t = 0; t <= tend; ++t) {
      if (t < T) {
        if (t >= 2)
          while (ldc(&cnt[3]) < t - 1) {}   // xS[t] ready (head phase t-2)
        const float* hp = &h0L[(t - 1) & 7][16 * k];
        f4 hv0 = *(const f4*)hp, hv1 = *(const f4*)(hp + 4);
        f4 hv2 = *(const f4*)(hp + 8), hv3 = *(const f4*)(hp + 12);
        float xg0 = 0, xg1 = 0, xg2 = 0, xg3 = 0;
        if (t >= 1) {
          xg0 = xS[0][t & 7][l]; xg1 = xS[1][t & 7][l];
          xg2 = xS[2][t & 7][l]; xg3 = xS[3][t & 7][l];
        }
        f2 acc[16];
        #pragma unroll
        for (int z = 0; z < 16; ++z) acc[z] = (f2){0.f, 0.f};
        f4 hv[4] = {hv0, hv1, hv2, hv3};
        #pragma unroll
        for (int c = 0; c < 4; ++c) {
          f4 v = hv[c];
          #pragma unroll
          for (int z = 0; z < 16; ++z) {
            acc[z] += wq[z * 8 + 2 * c] * v.lo;
            acc[z] += wq[z * 8 + 2 * c + 1] * v.hi;
          }
        }
        float Ps[16];
        #pragma unroll
        for (int z = 0; z < 16; ++z) Ps[z] = acc[z].x + acc[z].y;
        float G[4];
        #pragma unroll
        for (int j = 0; j < 4; ++j)
          G[j] = ((Ps[j] + qp<0x39>(Ps[12 + j])) +
                  (qp<0x4E>(Ps[8 + j]) + qp<0x93>(Ps[4 + j]))) + bg[j];
        G[0] += xg0; G[1] += xg1; G[2] += xg2; G[3] += xg3;
        float si = sigm(G[0]), sf = sigm(G[1]);
        float tg = tanhe(G[2]), so = sigm(G[3]);
        cS = sf * cS + si * tg;
        hS = so * tanhe(cS);
        h0L[t & 7][l] = hS;
      }
      if (l == 0) stc(&cnt[0], t + 1);
    }
  } else if (wv == 1) {
    // ---------------- layer 1, input half ----------------
    for (int t = 0; t <= tend; ++t) {
      if (t >= 1 && t <= T) {
        while (ldc(&cnt[0]) < t) {}        // h0[t-1] ready
        const float* hp = &h0L[(t - 1) & 7][16 * k];
        f4 hv[4] = {*(const f4*)hp, *(const f4*)(hp + 4),
                    *(const f4*)(hp + 8), *(const f4*)(hp + 12)};
        f2 acc[16];
        #pragma unroll
        for (int z = 0; z < 16; ++z) acc[z] = (f2){0.f, 0.f};
        #pragma unroll
        for (int c = 0; c < 4; ++c) {
          f4 v = hv[c];
          #pragma unroll
          for (int z = 0; z < 16; ++z) {
            acc[z] += wq[z * 8 + 2 * c] * v.lo;
            acc[z] += wq[z * 8 + 2 * c + 1] * v.hi;
          }
        }
        float Ps[16];
        #pragma unroll
        for (int z = 0; z < 16; ++z) Ps[z] = acc[z].x + acc[z].y;
        const int sl = (t - 1) & 7;
        #pragma unroll
        for (int j = 0; j < 4; ++j)
          Pld[j][sl][l] = (Ps[j] + qp<0x39>(Ps[12 + j])) +
                          (qp<0x4E>(Ps[8 + j]) + qp<0x93>(Ps[4 + j]));
      }
      if (l == 0) stc(&cnt[1], t + 1);
    }
  } else if (wv == 2) {
    // ---------------- layer 1, recurrent half + act ----------------
    for (int t = 0; t <= tend; ++t) {
      if (t >= 2 && t <= T + 1) {
        while (ldc(&cnt[1]) < t) {}        // P[t-2] ready
        const int sp = (t - 2) & 7;
        float Pg0 = Pld[0][sp][l], Pg1 = Pld[1][sp][l];
        float Pg2 = Pld[2][sp][l], Pg3 = Pld[3][sp][l];
        const float* hp = &h1L[(t - 3) & 7][16 * k];
        f4 hv[4] = {*(const f4*)hp, *(const f4*)(hp + 4),
                    *(const f4*)(hp + 8), *(const f4*)(hp + 12)};
        f2 acc[16];
        #pragma unroll
        for (int z = 0; z < 16; ++z) acc[z] = (f2){0.f, 0.f};
        #pragma unroll
        for (int c = 0; c < 4; ++c) {
          f4 v = hv[c];
          #pragma unroll
          for (int z = 0; z < 16; ++z) {
            acc[z] += wq[z * 8 + 2 * c] * v.lo;
            acc[z] += wq[z * 8 + 2 * c + 1] * v.hi;
          }
        }
        float Ps[16];
        #pragma unroll
        for (int z = 0; z < 16; ++z) Ps[z] = acc[z].x + acc[z].y;
        float G[4];
        #pragma unroll
        for (int j = 0; j < 4; ++j)
          G[j] = ((Ps[j] + qp<0x39>(Ps[12 + j])) +
                  (qp<0x4E>(Ps[8 + j]) + qp<0x93>(Ps[4 + j]))) + bg[j];
        G[0] += Pg0; G[1] += Pg1; G[2] += Pg2; G[3] += Pg3;
        float si = sigm(G[0]), sf = sigm(G[1]);
        float tg = tanhe(G[2]), so = sigm(G[3]);
        cS = sf * cS + si * tg;
        hS = so * tanhe(cS);
        h1L[(t - 2) & 7][l] = hS;
      }
      if (l == 0) stc(&cnt[2], t + 1);
    }
  } else {
    // ---------------- head: x-proj, hid+out, IO ----------------
    for (int t = 0; t <= tend; ++t) {
      // x-proj for step t+2 (uses target[t+1])
      if (t + 2 <= T - 1) {
        const f4* trow =
            (const f4*)&tbuf[((t + 1) >> 5) & 1][((t + 1) & 31) * NF];
        f4 r0 = trow[0], r1 = trow[1];
        const int sl = (t + 2) & 7;
        #pragma unroll
        for (int j = 0; j < 4; ++j) {
          f2 s = wq[j * 4 + 0] * r0.lo;
          s += wq[j * 4 + 1] * r0.hi;
          s += wq[j * 4 + 2] * r1.lo;
          s += wq[j * 4 + 3] * r1.hi;
          xS[j][sl][l] = xd4[j] + s.x + s.y;
        }
      }
      // hid + out for step s = t-4
      if (t >= 4) {
        while (ldc(&cnt[2]) < t - 1) {}    // h1[t-4] ready
        const float* hp = &h1L[(t - 4) & 7][16 * k];
        f4 hv[4] = {*(const f4*)hp, *(const f4*)(hp + 4),
                    *(const f4*)(hp + 8), *(const f4*)(hp + 12)};
        f2 a0 = {0.f, 0.f}, a1 = {0.f, 0.f};
        #pragma unroll
        for (int c = 0; c < 4; ++c) {
          f4 v = hv[c];
          a0 += wq[16 + 2 * c] * v.lo;     a0 += wq[16 + 2 * c + 1] * v.hi;
          a1 += wq[24 + 2 * c] * v.lo;     a1 += wq[24 + 2 * c + 1] * v.hi;
        }
        float A0 = a0.x + a0.y, A1 = a1.x + a1.y;
        float B = A0 + qp<0xB1>(A1);
        float S = B + qp<0x4E>(B);
        if (k < 2) hidb[2 * q + k] = S + bh_r;
        // out (reads all hidb written this phase; in-wave ordering)
        if (q < 8) {
          f4 ha = *(const f4*)&hidb[8 * k];
          f4 hb = *(const f4*)&hidb[8 * k + 4];
          f2 po = wq[32] * ha.lo;
          po += wq[33] * ha.hi;
          po += wq[34] * hb.lo;
          po += wq[35] * hb.hi;
          float so = po.x + po.y;
          so += qp<0xB1>(so);
          so += qp<0x4E>(so);
          if (k == 0) obuf[((t - 4) & 63) * NF + q] = rintf(so + bo_r);
        }
      }
      // IO
      if ((t & 31) == 4 && t >= 36) {
        const int s = (t - 36) + (l >> 1);
        const int off = (l & 1) * 4;
        *(f4*)&outp[s * NF + off] = *(const f4*)&obuf[(s & 63) * NF + off];
      }
      if ((t & 31) == 12) {
        const int cl = (t >> 5) + 1;
        if (cl * 32 < T)
          *(f4*)&tbuf[cl & 1][l * 4] = *(const f4*)&target[cl * 256 + l * 4];
      }
      if (l == 0) stc(&cnt[3], t + 1);
    }
  }
  __syncthreads();

  // ================= EPILOGUE =================
  {
    int tstar = (T + 3) - ((T - 1) & 31);   // last flush phase (>=36 for big T)
    int s0 = (tstar >= 36) ? (tstar - 4) : 0;
    for (int idx = tid; idx < (T - s0) * NF; idx += 256) {
      const int s = s0 + (idx >> 3);
      outp[s * NF + (idx & 7)] = obuf[(s & 63) * NF + (idx & 7)];
    }
  }
  const int base = T * NF;
  if (wv == 0) {
    outp[base + l]       = hS;   // h_final layer 0
    outp[base + 128 + l] = cS;   // c_final layer 0
  } else if (wv == 2) {
    outp[base + 64 + l]  = hS;   // h_final layer 1
    outp[base + 192 + l] = cS;   // c_final layer 1
  }
}

extern "C" void kernel_launch(void* const* d_in, const int* in_sizes, int n_in,
                              void* d_out, int out_size, void* d_ws, size_t ws_size,
                              hipStream_t stream) {
  const float* h0in   = (const float*)d_in[1];
  const float* c0in   = (const float*)d_in[2];
  const float* diffp  = (const float*)d_in[3];
  const float* target = (const float*)d_in[4];
  const float* Wih0   = (const float*)d_in[5];
  const float* Whh0   = (const float*)d_in[6];
  const float* bih0   = (const float*)d_in[7];
  const float* bhh0   = (const float*)d_in[8];
  const float* Wih1   = (const float*)d_in[9];
  const float* Whh1   = (const float*)d_in[10];
  const float* bih1   = (const float*)d_in[11];
  const float* bhh1   = (const float*)d_in[12];
  const float* Whid   = (const float*)d_in[13];
  const float* bhidp  = (const float*)d_in[14];
  const float* Woutp  = (const float*)d_in[15];
  const float* boutp  = (const float*)d_in[16];
  float* outp = (float*)d_out;
  const int T = in_sizes[4] / NF;

  decoder_p8<<<dim3(1), dim3(256), 0, stream>>>(
      h0in, c0in, diffp, target,
      Wih0, Whh0, bih0, bhh0,
      Wih1, Whh1, bih1, bhh1,
      Whid, bhidp, Woutp, boutp,
      outp, T);
}